// Round 6
// baseline (196.722 us; speedup 1.0000x reference)
//
#include <hip/hip_runtime.h>

// Problem constants (fixed by setup_inputs)
constexpr int BATCH = 8;
constexpr int NPB   = 1 << 20;       // N per batch
constexpr int BS    = 128;           // block_size
constexpr int NB    = NPB / BS;      // 8192 node-blocks per batch
constexpr int NBLK  = BATCH * NB;    // 65536 total node-blocks
constexpr int MAXKV = 32;

#define GRAPH_WEIGHT 0.3f

constexpr int P1_WGS = (BATCH * NPB) / (256 * 16);  // 2048 wgs, 16 elems/thread
constexpr int P2_WGS = 2048;                        // 32 node-blocks per wg

// Workspace layout (floats). All data slots fully overwritten each call;
// completion counters are zeroed by phase1 (ws is poisoned 0xAA).
constexpr int WS_BSC = 0;                    // float2[NBLK] {sum keep*p, keep cnt}
constexpr int WS_QUP = 2 * NBLK;             // float4[NBLK] {q, sum u*p, sum u*p^2, 0}
constexpr int WS_SUP = WS_QUP + 4 * NBLK;    // float2[P1_WGS] {sup_sum, sup_cnt}
constexpr int WS_P2  = WS_SUP + 2 * P1_WGS;  // float4[P2_WGS] {L, C, U, 0}
constexpr int WS_CNT = WS_P2 + 4 * P2_WGS;   // 33 counters, 32-float stride

typedef float v4f __attribute__((ext_vector_type(4)));
typedef int   v4i __attribute__((ext_vector_type(4)));

// ---------------- Phase 1: per-element pass + per-block stats ----------------
// 16 elems/thread, ALL 16 nontemporal 16B loads burst-issued before compute
// (16KB in flight per wave; retry of R3's hoist now that nt bypasses the L1
// miss-tracking cap that made it regress). One wave = 1024 elems = 8 blocks;
// lanes 8g..8g+7 own block g (3-stage xor reduce).
__global__ __launch_bounds__(256) void k_phase1(const v4f* __restrict__ lg4,
                                                const v4f* __restrict__ tg4,
                                                const v4i* __restrict__ sm4,
                                                const v4i* __restrict__ im4,
                                                float* __restrict__ ws)
{
    // zero the phase2 completion counters (33 x 128B-strided)
    if (blockIdx.x == 0 && threadIdx.x < 33)
        reinterpret_cast<unsigned*>(ws)[WS_CNT + threadIdx.x * 32] = 0u;

    const int lane = threadIdx.x & 63;
    const int wid  = (blockIdx.x << 2) + (threadIdx.x >> 6); // global wave id
    const int grp  = lane >> 3;                  // block within wave (0..7)
    const int sub  = lane & 7;                   // sub-lane within block group
    const int blk  = (wid << 3) + grp;           // node-block id (0..NBLK-1)
    const int c0   = (blk << 5) + sub;           // float4-chunk index (32/block)

    v4f xv[4], tv[4];
    v4i sv[4], gv[4];
#pragma unroll
    for (int j = 0; j < 4; ++j) xv[j] = __builtin_nontemporal_load(lg4 + c0 + (j << 3));
#pragma unroll
    for (int j = 0; j < 4; ++j) tv[j] = __builtin_nontemporal_load(tg4 + c0 + (j << 3));
#pragma unroll
    for (int j = 0; j < 4; ++j) sv[j] = __builtin_nontemporal_load(sm4 + c0 + (j << 3));
#pragma unroll
    for (int j = 0; j < 4; ++j) gv[j] = __builtin_nontemporal_load(im4 + c0 + (j << 3));

    float sup_sum = 0.f, sup_cnt = 0.f;
    float bsum = 0.f, bcnt = 0.f, q = 0.f, up = 0.f, up2 = 0.f;

#pragma unroll
    for (int j = 0; j < 4; ++j) {
#pragma unroll
        for (int k = 0; k < 4; ++k) {
            const float x = xv[j][k], t = tv[j][k];
            const bool s = (sv[j][k] != 0);
            const bool g = (gv[j][k] != 0);

            const float ax  = fabsf(x);
            const float e   = __expf(-ax);          // (0,1]
            const float lp  = __logf(1.f + e);      // log1p(exp(-|x|))
            const float per = fmaxf(x, 0.f) - x * t + lp;
            const float inv = 1.f / (1.f + e);
            const float p   = (x >= 0.f) ? inv : e * inv;   // sigmoid(x)

            if (s) { sup_sum += per; sup_cnt += 1.f; }
            if (!g) { bsum += p; bcnt += 1.f; }
            if (!g && !s) { q += 1.f; up += p; up2 += p * p; }
        }
    }

    // block stats: reduce over the 8-lane group (d = 4,2,1)
#pragma unroll
    for (int d = 4; d >= 1; d >>= 1) {
        bsum += __shfl_xor(bsum, d);
        bcnt += __shfl_xor(bcnt, d);
        q    += __shfl_xor(q, d);
        up   += __shfl_xor(up, d);
        up2  += __shfl_xor(up2, d);
    }
    if (sub == 0) {
        *reinterpret_cast<float2*>(ws + WS_BSC + 2 * blk) = make_float2(bsum, bcnt);
        *reinterpret_cast<float4*>(ws + WS_QUP + 4 * blk) = make_float4(q, up, up2, 0.f);
    }

    // sup terms: full-wave reduction, one plain float2 store per workgroup
#pragma unroll
    for (int d = 32; d >= 1; d >>= 1) {
        sup_sum += __shfl_xor(sup_sum, d);
        sup_cnt += __shfl_xor(sup_cnt, d);
    }
    __shared__ float lsup[4][2];
    const int w = threadIdx.x >> 6;
    if (lane == 0) { lsup[w][0] = sup_sum; lsup[w][1] = sup_cnt; }
    __syncthreads();
    if (threadIdx.x == 0) {
        const float a = lsup[0][0] + lsup[1][0] + lsup[2][0] + lsup[3][0];
        const float b = lsup[0][1] + lsup[1][1] + lsup[2][1] + lsup[3][1];
        *reinterpret_cast<float2*>(ws + WS_SUP + 2 * blockIdx.x) = make_float2(a, b);
    }
}

// ---------------- Phase 2 (+fused final reduce) ----------------
// 32 node-blocks per wg as in R5. After writing its float4 partial, each wg
// signals a 2-level completion counter (32 striped sub-counters -> master;
// <=64 serialized RMWs per line). The last wg performs the final reduction.
__global__ __launch_bounds__(256) void k_phase2(const int* __restrict__ kvi,
                                                const int* __restrict__ kvn,
                                                float* __restrict__ ws,
                                                float* __restrict__ out)
{
    const int tid    = threadIdx.x;
    const int hw     = tid >> 5;                // half-wave 0..7
    const int lane32 = tid & 31;
    const int h0     = blockIdx.x * 32 + hw * 4;          // first of 4 blocks
    const int bbase  = (blockIdx.x >> 8) << 13;           // batch * NB

    const v4i nkv4 = *reinterpret_cast<const v4i*>(kvn + h0);

    int idxs[4];
#pragma unroll
    for (int j = 0; j < 4; ++j)
        idxs[j] = __builtin_nontemporal_load(kvi + (size_t)(h0 + j) * MAXKV + lane32);

    float gsv[4], gcv[4];
#pragma unroll
    for (int j = 0; j < 4; ++j) {
        float gs = 0.f, gc = 0.f;
        if (lane32 < nkv4[j]) {
            const float2 v = *reinterpret_cast<const float2*>(ws + WS_BSC + 2 * (bbase + idxs[j]));
            gs = v.x; gc = v.y;
        }
#pragma unroll
        for (int d = 16; d >= 1; d >>= 1) {
            gs += __shfl_xor(gs, d);
            gc += __shfl_xor(gc, d);
        }
        gsv[j] = gs; gcv[j] = gc;
    }

    float L = 0.f, C = 0.f, U = 0.f;
    if (lane32 < 4) {
        const int k = lane32;
        const float4 quv = *reinterpret_cast<const float4*>(ws + WS_QUP + 4 * (h0 + k));
        const float q = quv.x, up = quv.y, up2 = quv.z;
        const float gs = gsv[k], gc = gcv[k];
        const float m  = gs / fmaxf(gc, 1.f);
        const bool  vb = (q > 0.f) && (nkv4[k] > 0) && (gc > 0.f);
        const float sq = up2 - 2.f * m * up + m * m * q;  // sum_u (p-m)^2
        L = vb ? sq : 0.f;
        C = vb ? q  : 0.f;
        U = q;                                   // unconditional: uncertain.any()
    }
#pragma unroll
    for (int d = 2; d >= 1; d >>= 1) {
        L += __shfl_xor(L, d);
        C += __shfl_xor(C, d);
        U += __shfl_xor(U, d);
    }

    __shared__ float l2s[8][3];
    __shared__ bool  is_last;
    if (lane32 == 0) { l2s[hw][0] = L; l2s[hw][1] = C; l2s[hw][2] = U; }
    __syncthreads();
    if (tid == 0) {
        float Ls = 0.f, Cs = 0.f, Us = 0.f;
#pragma unroll
        for (int j = 0; j < 8; ++j) { Ls += l2s[j][0]; Cs += l2s[j][1]; Us += l2s[j][2]; }
        *reinterpret_cast<float4*>(ws + WS_P2 + 4 * blockIdx.x) = make_float4(Ls, Cs, Us, 0.f);

        __threadfence();   // make partial visible device-wide before signaling
        unsigned* cnts = reinterpret_cast<unsigned*>(ws) + WS_CNT;
        const unsigned prev = atomicAdd(cnts + (blockIdx.x & 31) * 32, 1u);
        bool last = false;
        if (prev == (P2_WGS / 32) - 1) {        // stripe complete
            const unsigned pm = atomicAdd(cnts + 32 * 32, 1u);
            last = (pm == 31);                   // all stripes complete
        }
        is_last = last;
    }
    __syncthreads();
    if (!is_last) return;

    // ---------------- fused final reduce (one workgroup) ----------------
    __threadfence();  // acquire: order reads after observed completions
    const int lane = tid & 63;
    const int w    = tid >> 6;                   // wave 0..3

    __shared__ float fsup[4][2];
    __shared__ float ffin[8][3];

    // sup partials: 2048 float2 = 1024 float4 {s,c,s,c}; 4 float4/thread
    const v4f* supf4 = reinterpret_cast<const v4f*>(ws + WS_SUP);
    float ss = 0.f, sc = 0.f;
#pragma unroll
    for (int j = 0; j < 4; ++j) {
        const v4f v = supf4[tid * 4 + j];
        ss += v.x + v.z; sc += v.y + v.w;
    }
#pragma unroll
    for (int d = 32; d >= 1; d >>= 1) { ss += __shfl_xor(ss, d); sc += __shfl_xor(sc, d); }
    if (lane == 0) { fsup[w][0] = ss; fsup[w][1] = sc; }

    // p2 partials: batch b owns slots [b*256, b*256+256); wave w -> batches 2w,2w+1
    const v4f* p2f4 = reinterpret_cast<const v4f*>(ws + WS_P2);
#pragma unroll
    for (int bb = 0; bb < 2; ++bb) {
        const int b = 2 * w + bb;
        float Lb = 0.f, Cb = 0.f, Ub = 0.f;
#pragma unroll
        for (int j = 0; j < 4; ++j) {
            const v4f v = p2f4[b * 256 + lane * 4 + j];
            Lb += v.x; Cb += v.y; Ub += v.z;
        }
#pragma unroll
        for (int d = 32; d >= 1; d >>= 1) {
            Lb += __shfl_xor(Lb, d);
            Cb += __shfl_xor(Cb, d);
            Ub += __shfl_xor(Ub, d);
        }
        if (lane == 0) { ffin[b][0] = Lb; ffin[b][1] = Cb; ffin[b][2] = Ub; }
    }
    __syncthreads();

    if (tid == 0) {
        float ssum = 0.f, scn = 0.f;
#pragma unroll
        for (int j = 0; j < 4; ++j) { ssum += fsup[j][0]; scn += fsup[j][1]; }
        float per = 0.f, nv = 0.f, uc = 0.f;
#pragma unroll
        for (int b = 0; b < 8; ++b) {
            const float l = ffin[b][0], c = ffin[b][1], u = ffin[b][2];
            if (c > 0.f) { per += l / fmaxf(c, 1.f); nv += 1.f; }
            uc += u;
        }
        const float loss_sup = (scn > 0.f) ? ssum / fmaxf(scn, 1.f) : 0.f;
        float lgr = per / fmaxf(nv, 1.f);
        if (!(uc > 0.f)) lgr = 0.f;
        out[0] = loss_sup + GRAPH_WEIGHT * lgr;
    }
}

extern "C" void kernel_launch(void* const* d_in, const int* in_sizes, int n_in,
                              void* d_out, int out_size, void* d_ws, size_t ws_size,
                              hipStream_t stream) {
    const v4f* lg4 = (const v4f*)d_in[0];  // logits  [B,N,1]
    const v4f* tg4 = (const v4f*)d_in[1];  // targets [B,N]
    const v4i* sm4 = (const v4i*)d_in[2];  // sup_mask (int32)
    const v4i* im4 = (const v4i*)d_in[3];  // ignore_mask (int32)
    const int* kvi = (const int*)d_in[4];  // kv_indices [B,NB,MAXKV]
    const int* kvn = (const int*)d_in[5];  // kv_num_blocks [B,NB]
    float* ws  = (float*)d_ws;
    float* out = (float*)d_out;

    // 2 dispatches: phase1, then phase2 with fused final reduce.
    k_phase1<<<P1_WGS, 256, 0, stream>>>(lg4, tg4, sm4, im4, ws);
    k_phase2<<<P2_WGS, 256, 0, stream>>>(kvi, kvn, ws, out);
}

// Round 7
// 163.812 us; speedup vs baseline: 1.2009x; 1.2009x over previous
//
#include <hip/hip_runtime.h>

// Problem constants (fixed by setup_inputs)
constexpr int BATCH = 8;
constexpr int NPB   = 1 << 20;       // N per batch
constexpr int BS    = 128;           // block_size
constexpr int NB    = NPB / BS;      // 8192 node-blocks per batch
constexpr int NBLK  = BATCH * NB;    // 65536 total node-blocks
constexpr int MAXKV = 32;

#define GRAPH_WEIGHT 0.3f

constexpr int P1_WGS = (BATCH * NPB) / (256 * 16);  // 2048 wgs, 16 elems/thread
constexpr int P2_WGS = 2048;                        // 32 node-blocks per wg

// Workspace layout (floats). Every slot fully overwritten each call ->
// no memset dispatch, no atomics, no fences (kernel-boundary release gives
// cross-XCD visibility for free; R6 showed in-kernel fences cost ~42us).
constexpr int WS_BSC = 0;                    // float2[NBLK] {sum keep*p, keep cnt}
constexpr int WS_QUP = 2 * NBLK;             // float4[NBLK] {q, sum u*p, sum u*p^2, 0}
constexpr int WS_SUP = WS_QUP + 4 * NBLK;    // float2[P1_WGS] {sup_sum, sup_cnt}
constexpr int WS_P2  = WS_SUP + 2 * P1_WGS;  // float4[P2_WGS] {L, C, U, 0}

typedef float v4f __attribute__((ext_vector_type(4)));
typedef int   v4i __attribute__((ext_vector_type(4)));

// ---------------- Phase 1: per-element pass + per-block stats ----------------
// 16 elems/thread, ALL 16 nontemporal 16B loads burst-issued before compute
// (16KB in flight per wave — deep read bursts under nt are the one software
// lever on the read-concurrency cap; R6 data suggests ~9us gain vs 8/thread).
// One wave = 1024 elems = 8 blocks; lanes 8g..8g+7 own block g.
__global__ __launch_bounds__(256) void k_phase1(const v4f* __restrict__ lg4,
                                                const v4f* __restrict__ tg4,
                                                const v4i* __restrict__ sm4,
                                                const v4i* __restrict__ im4,
                                                float* __restrict__ ws)
{
    const int lane = threadIdx.x & 63;
    const int wid  = (blockIdx.x << 2) + (threadIdx.x >> 6); // global wave id
    const int grp  = lane >> 3;                  // block within wave (0..7)
    const int sub  = lane & 7;                   // sub-lane within block group
    const int blk  = (wid << 3) + grp;           // node-block id (0..NBLK-1)
    const int c0   = (blk << 5) + sub;           // float4-chunk index (32/block)

    v4f xv[4], tv[4];
    v4i sv[4], gv[4];
#pragma unroll
    for (int j = 0; j < 4; ++j) xv[j] = __builtin_nontemporal_load(lg4 + c0 + (j << 3));
#pragma unroll
    for (int j = 0; j < 4; ++j) tv[j] = __builtin_nontemporal_load(tg4 + c0 + (j << 3));
#pragma unroll
    for (int j = 0; j < 4; ++j) sv[j] = __builtin_nontemporal_load(sm4 + c0 + (j << 3));
#pragma unroll
    for (int j = 0; j < 4; ++j) gv[j] = __builtin_nontemporal_load(im4 + c0 + (j << 3));

    float sup_sum = 0.f, sup_cnt = 0.f;
    float bsum = 0.f, bcnt = 0.f, q = 0.f, up = 0.f, up2 = 0.f;

#pragma unroll
    for (int j = 0; j < 4; ++j) {
#pragma unroll
        for (int k = 0; k < 4; ++k) {
            const float x = xv[j][k], t = tv[j][k];
            const bool s = (sv[j][k] != 0);
            const bool g = (gv[j][k] != 0);

            const float ax  = fabsf(x);
            const float e   = __expf(-ax);          // (0,1]
            const float lp  = __logf(1.f + e);      // log1p(exp(-|x|))
            const float per = fmaxf(x, 0.f) - x * t + lp;
            const float inv = 1.f / (1.f + e);
            const float p   = (x >= 0.f) ? inv : e * inv;   // sigmoid(x)

            if (s) { sup_sum += per; sup_cnt += 1.f; }
            if (!g) { bsum += p; bcnt += 1.f; }
            if (!g && !s) { q += 1.f; up += p; up2 += p * p; }
        }
    }

    // block stats: reduce over the 8-lane group (d = 4,2,1)
#pragma unroll
    for (int d = 4; d >= 1; d >>= 1) {
        bsum += __shfl_xor(bsum, d);
        bcnt += __shfl_xor(bcnt, d);
        q    += __shfl_xor(q, d);
        up   += __shfl_xor(up, d);
        up2  += __shfl_xor(up2, d);
    }
    if (sub == 0) {
        *reinterpret_cast<float2*>(ws + WS_BSC + 2 * blk) = make_float2(bsum, bcnt);
        *reinterpret_cast<float4*>(ws + WS_QUP + 4 * blk) = make_float4(q, up, up2, 0.f);
    }

    // sup terms: full-wave reduction, one plain float2 store per workgroup
#pragma unroll
    for (int d = 32; d >= 1; d >>= 1) {
        sup_sum += __shfl_xor(sup_sum, d);
        sup_cnt += __shfl_xor(sup_cnt, d);
    }
    __shared__ float lsup[4][2];
    const int w = threadIdx.x >> 6;
    if (lane == 0) { lsup[w][0] = sup_sum; lsup[w][1] = sup_cnt; }
    __syncthreads();
    if (threadIdx.x == 0) {
        const float a = lsup[0][0] + lsup[1][0] + lsup[2][0] + lsup[3][0];
        const float b = lsup[0][1] + lsup[1][1] + lsup[2][1] + lsup[3][1];
        *reinterpret_cast<float2*>(ws + WS_SUP + 2 * blockIdx.x) = make_float2(a, b);
    }
}

// ---------------- Phase 2: neighbor gather, 32 node-blocks per wg ----------
// (R5 version — proven <6us.) Each 32-lane half-wave handles 4 consecutive
// node-blocks; one plain float4 partial per wg. No atomics, no fences.
__global__ __launch_bounds__(256) void k_phase2(const int* __restrict__ kvi,
                                                const int* __restrict__ kvn,
                                                float* __restrict__ ws)
{
    const int hw     = threadIdx.x >> 5;        // half-wave 0..7
    const int lane32 = threadIdx.x & 31;
    const int h0     = blockIdx.x * 32 + hw * 4;          // first of 4 blocks
    const int bbase  = (blockIdx.x >> 8) << 13;           // batch * NB

    const v4i nkv4 = *reinterpret_cast<const v4i*>(kvn + h0);

    int idxs[4];
#pragma unroll
    for (int j = 0; j < 4; ++j)
        idxs[j] = __builtin_nontemporal_load(kvi + (size_t)(h0 + j) * MAXKV + lane32);

    float gsv[4], gcv[4];
#pragma unroll
    for (int j = 0; j < 4; ++j) {
        float gs = 0.f, gc = 0.f;
        if (lane32 < nkv4[j]) {
            const float2 v = *reinterpret_cast<const float2*>(ws + WS_BSC + 2 * (bbase + idxs[j]));
            gs = v.x; gc = v.y;
        }
#pragma unroll
        for (int d = 16; d >= 1; d >>= 1) {
            gs += __shfl_xor(gs, d);
            gc += __shfl_xor(gc, d);
        }
        gsv[j] = gs; gcv[j] = gc;   // every lane now holds block j's totals
    }

    // lanes 0..3: finalize block h0+lane (coalesced 64B QUP read)
    float L = 0.f, C = 0.f, U = 0.f;
    if (lane32 < 4) {
        const int k = lane32;
        const float4 quv = *reinterpret_cast<const float4*>(ws + WS_QUP + 4 * (h0 + k));
        const float q = quv.x, up = quv.y, up2 = quv.z;
        const float gs = gsv[k], gc = gcv[k];
        const float m  = gs / fmaxf(gc, 1.f);
        const bool  vb = (q > 0.f) && (nkv4[k] > 0) && (gc > 0.f);
        const float sq = up2 - 2.f * m * up + m * m * q;  // sum_u (p-m)^2
        L = vb ? sq : 0.f;
        C = vb ? q  : 0.f;
        U = q;                                   // unconditional: uncertain.any()
    }
#pragma unroll
    for (int d = 2; d >= 1; d >>= 1) {
        L += __shfl_xor(L, d);
        C += __shfl_xor(C, d);
        U += __shfl_xor(U, d);
    }

    __shared__ float l2s[8][3];
    if (lane32 == 0) { l2s[hw][0] = L; l2s[hw][1] = C; l2s[hw][2] = U; }
    __syncthreads();
    if (threadIdx.x == 0) {
        float Ls = 0.f, Cs = 0.f, Us = 0.f;
#pragma unroll
        for (int j = 0; j < 8; ++j) { Ls += l2s[j][0]; Cs += l2s[j][1]; Us += l2s[j][2]; }
        *reinterpret_cast<float4*>(ws + WS_P2 + 4 * blockIdx.x) = make_float4(Ls, Cs, Us, 0.f);
    }
}

// ---------------- Phase 3: final reduce (one 512-thread workgroup) ----------
__global__ __launch_bounds__(512) void k_phase3(const float* __restrict__ ws,
                                                float* __restrict__ out)
{
    const int tid  = threadIdx.x;          // 0..511
    const int lane = tid & 63;
    const int w    = tid >> 6;             // wave 0..7

    __shared__ float lsup[8][2];
    __shared__ float lfin[8][3];

    // sup partials: 2048 float2 = 1024 float4 {s,c,s,c}; 2 float4/thread
    const v4f* supf4 = reinterpret_cast<const v4f*>(ws + WS_SUP);
    float ss = 0.f, sc = 0.f;
#pragma unroll
    for (int j = 0; j < 2; ++j) {
        const v4f v = supf4[tid * 2 + j];
        ss += v.x + v.z; sc += v.y + v.w;
    }
#pragma unroll
    for (int d = 32; d >= 1; d >>= 1) { ss += __shfl_xor(ss, d); sc += __shfl_xor(sc, d); }
    if (lane == 0) { lsup[w][0] = ss; lsup[w][1] = sc; }

    // p2 partials: wave w handles batch w: slots [w*256, w*256+256), 4/lane
    const v4f* p2f4 = reinterpret_cast<const v4f*>(ws + WS_P2);
    float L = 0.f, C = 0.f, U = 0.f;
#pragma unroll
    for (int j = 0; j < 4; ++j) {
        const v4f v = p2f4[w * 256 + lane * 4 + j];
        L += v.x; C += v.y; U += v.z;
    }
#pragma unroll
    for (int d = 32; d >= 1; d >>= 1) {
        L += __shfl_xor(L, d);
        C += __shfl_xor(C, d);
        U += __shfl_xor(U, d);
    }
    if (lane == 0) { lfin[w][0] = L; lfin[w][1] = C; lfin[w][2] = U; }
    __syncthreads();

    if (tid == 0) {
        float ssum = 0.f, scn = 0.f;
#pragma unroll
        for (int j = 0; j < 8; ++j) { ssum += lsup[j][0]; scn += lsup[j][1]; }
        float per = 0.f, nv = 0.f, uc = 0.f;
#pragma unroll
        for (int b = 0; b < 8; ++b) {
            const float l = lfin[b][0], c = lfin[b][1], u = lfin[b][2];
            if (c > 0.f) { per += l / fmaxf(c, 1.f); nv += 1.f; }
            uc += u;
        }
        const float loss_sup = (scn > 0.f) ? ssum / fmaxf(scn, 1.f) : 0.f;
        float lgr = per / fmaxf(nv, 1.f);
        if (!(uc > 0.f)) lgr = 0.f;
        out[0] = loss_sup + GRAPH_WEIGHT * lgr;
    }
}

extern "C" void kernel_launch(void* const* d_in, const int* in_sizes, int n_in,
                              void* d_out, int out_size, void* d_ws, size_t ws_size,
                              hipStream_t stream) {
    const v4f* lg4 = (const v4f*)d_in[0];  // logits  [B,N,1]
    const v4f* tg4 = (const v4f*)d_in[1];  // targets [B,N]
    const v4i* sm4 = (const v4i*)d_in[2];  // sup_mask (int32)
    const v4i* im4 = (const v4i*)d_in[3];  // ignore_mask (int32)
    const int* kvi = (const int*)d_in[4];  // kv_indices [B,NB,MAXKV]
    const int* kvn = (const int*)d_in[5];  // kv_num_blocks [B,NB]
    float* ws  = (float*)d_ws;
    float* out = (float*)d_out;

    k_phase1<<<P1_WGS, 256, 0, stream>>>(lg4, tg4, sm4, im4, ws);
    k_phase2<<<P2_WGS, 256, 0, stream>>>(kvi, kvn, ws);
    k_phase3<<<1, 512, 0, stream>>>(ws, out);
}